// Round 9
// baseline (264.692 us; speedup 1.0000x reference)
//
#include <hip/hip_runtime.h>
#include <hip/hip_fp16.h>
#include <math.h>

#define N_NODES 100000
#define N_EDGES 3200000
#define DIM 16
#define NSZ (N_NODES * DIM)

#define NPB 128         // nodes per bucket (bucket = col>>7, cl = col&127)
#define NBUCK 782       // ceil(100000/128); max col>>7 = 781
#define NBLK 512        // partition blocks
#define EPB 6250        // edges per partition block: 512*6250 = 3.2M exactly
#define CAP 6144        // aggregate LDS edge capacity (mean 4092, +32 sigma safe)

typedef float nvec4 __attribute__((ext_vector_type(4)));

// ---- 0) state f32 -> f16 (3.2MB: per-XCD-L2 resident; halves gather bytes) ----
__global__ __launch_bounds__(256)
void to_half(const float* __restrict__ state, __half* __restrict__ hs) {
    int i = blockIdx.x * 256 + threadIdx.x;
    if (i >= NSZ / 4) return;
    nvec4 v = __builtin_nontemporal_load(&((const nvec4*)state)[i]);
    union { __half2 h[2]; float2 f; } u;
    u.h[0] = __floats2half2_rn(v.x, v.y);
    u.h[1] = __floats2half2_rn(v.z, v.w);
    ((float2*)hs)[i] = u.f;
}

// ---- 1) local sort: each block owns edges [blk*EPB, (blk+1)*EPB), sorts them
//         by bucket in LDS, writes to ITS OWN packed slice (dense, coalesced)
//         + a u16 table row of local bucket starts. ZERO global atomics. ----
__global__ __launch_bounds__(512)
void local_sort(const int* __restrict__ row, const int* __restrict__ col,
                const float* __restrict__ w,
                unsigned long long* __restrict__ packed,
                unsigned short* __restrict__ tableA) {
    __shared__ unsigned long long sbuf[EPB];   // 50,000 B
    __shared__ int sc[1024];                   // scan scratch -> lstart
    __shared__ int hcnt[NBUCK];                // counts -> intra-block cursor
    int t = threadIdx.x, blk = blockIdx.x;
    int e0 = blk * EPB;

    for (int j = t; j < NBUCK; j += 512) hcnt[j] = 0;
    __syncthreads();
    for (int i = t; i < EPB; i += 512)         // p1: histogram (L2 keeps lines)
        atomicAdd(&hcnt[col[e0 + i] >> 7], 1);
    __syncthreads();
    sc[t]       = (t < NBUCK)       ? hcnt[t]       : 0;   // p2: scan 1024
    sc[t + 512] = (t + 512 < NBUCK) ? hcnt[t + 512] : 0;
    __syncthreads();
    for (int d = 1; d < 1024; d <<= 1) {
        int u1 = (t >= d) ? sc[t - d] : 0;
        int u2 = sc[t + 512 - d];              // t+512 >= d always (d<=512)
        __syncthreads();
        sc[t] += u1;
        sc[t + 512] += u2;
        __syncthreads();
    }
    for (int j = t; j < NBUCK; j += 512) {     // inclusive -> exclusive lstart
        int c = hcnt[j];
        int ex = sc[j] - c;
        sc[j] = ex;
        tableA[blk * NBUCK + j] = (unsigned short)ex;   // coalesced row write
        hcnt[j] = 0;                           // reuse as intra-block cursor
    }
    __syncthreads();
    for (int i = t; i < EPB; i += 512) {       // p3: LDS scatter (sorted)
        int e = e0 + i;
        int c = col[e];
        int b = c >> 7;
        int pos = sc[b] + atomicAdd(&hcnt[b], 1);
        unsigned hi = ((unsigned)row[e] << 7) | (unsigned)(c & 127);
        sbuf[pos] = ((unsigned long long)hi << 32) | __float_as_uint(w[e]);
    }
    __syncthreads();
    for (int i = t; i < EPB; i += 512)         // p4: dense coalesced sweep out
        __builtin_nontemporal_store(sbuf[i], &packed[e0 + i]);
}

// ---- 2) transpose table [blk][bucket] -> [bucket][blk] (0.8MB, trivial) ----
__global__ __launch_bounds__(256)
void transpose_tbl(const unsigned short* __restrict__ tableA,
                   unsigned short* __restrict__ T) {
    int o = blockIdx.x * 256 + threadIdx.x;    // o = b*NBLK + blk
    if (o >= NBUCK * NBLK) return;
    int b = o >> 9, blk = o & 511;             // NBLK = 512
    T[o] = tableA[blk * NBUCK + b];
}

// ---- 3) per-bucket: gather 512 segments, cl-sort in LDS, owner-computes ----
__global__ __launch_bounds__(512)
void seg_aggregate(const float* __restrict__ state,
                   const __half2* __restrict__ hs2,
                   const unsigned long long* __restrict__ packed,
                   const unsigned short* __restrict__ T,
                   float* __restrict__ out) {
    __shared__ unsigned long long sbuf[CAP];       // 48KB cl-sorted edges
    __shared__ int s_cnt[NPB], s_start[NPB], s_cur[NPB];
    __shared__ unsigned short segst[NBLK], segen[NBLK];
    int b = blockIdx.x, t = threadIdx.x;
    int g = t >> 3, q = t & 7;                     // 64 groups x 8 lanes

    segst[t] = T[b * NBLK + t];                    // coalesced 1KB
    segen[t] = (b == NBUCK - 1) ? (unsigned short)EPB : T[(b + 1) * NBLK + t];
    if (t < NPB) s_cnt[t] = 0;
    __syncthreads();

    // pass 1: cl histogram — thread t walks segment t, reads hi words only
    {
        int st = segst[t], en = segen[t];
        const unsigned* ph = (const unsigned*)packed;
        long base = (long)t * EPB;
        for (int e = st; e < en; ++e) {
            unsigned hi = ph[((base + e) << 1) + 1];
            atomicAdd(&s_cnt[hi & 127u], 1);
        }
    }
    __syncthreads();
    if (t < NPB) s_start[t] = s_cnt[t];
    __syncthreads();
    for (int d = 1; d < NPB; d <<= 1) {            // Hillis-Steele over 128
        int u = 0;
        if (t < NPB && t >= d) u = s_start[t - d];
        __syncthreads();
        if (t < NPB) s_start[t] += u;
        __syncthreads();
    }
    if (t < NPB) {
        int ex = s_start[t] - s_cnt[t];
        s_start[t] = ex;
        s_cur[t] = ex;
    }
    __syncthreads();
    // pass 2: re-walk (L2-hot), scatter into sbuf grouped by cl
    {
        int st = segst[t], en = segen[t];
        long base = (long)t * EPB;
        for (int e = st; e < en; ++e) {
            unsigned long long p = packed[base + e];
            int cl = (int)((p >> 32) & 127u);
            int pos = atomicAdd(&s_cur[cl], 1);
            if (pos < CAP) sbuf[pos] = p;
        }
    }
    __syncthreads();

    // owner-computes: group g owns nodes b*128 + {g, 64+g}; lane q = dim pair q
    float2 acc[2] = {make_float2(0.f, 0.f), make_float2(0.f, 0.f)};
    float2 x2[2];
    int nn[2]; bool valid[2];
    #pragma unroll
    for (int r = 0; r < 2; ++r) {
        int n = b * NPB + r * 64 + g;
        valid[r] = (n < N_NODES);
        nn[r] = n;
        x2[r] = valid[r] ? ((const float2*)state)[n * 8 + q]
                         : make_float2(0.f, 0.f);
    }
    #pragma unroll
    for (int r = 0; r < 2; ++r) {
        int j = r * 64 + g;
        int es = s_start[j];
        int ee = s_cur[j]; if (ee > CAP) ee = CAP;
        float2 a = acc[r], xx = x2[r];
        for (int e = es; e < ee; ++e) {
            unsigned long long p = sbuf[e];        // 8-lane broadcast read
            float we = __uint_as_float((unsigned)p);
            int rn = (int)(p >> 39);
            float2 f = __half22float2(hs2[rn * 8 + q]);   // 4B, 32B/group
            a.x += __sinf(f.x - xx.x) * we;
            a.y += __sinf(f.y - xx.y) * we;
        }
        acc[r] = a;
    }

    #pragma unroll
    for (int r = 0; r < 2; ++r) {
        if (!valid[r]) continue;
        float2 a = acc[r], xx = x2[r];
        float2 th = make_float2(tanhf(a.x), tanhf(a.y));
        int gdx = nn[r] * 8 + q;
        ((float2*)(out + 0 * (size_t)NSZ))[gdx] = make_float2(th.x - xx.x, th.y - xx.y);
        ((float2*)(out + 1 * (size_t)NSZ))[gdx] = xx;
        ((float2*)(out + 2 * (size_t)NSZ))[gdx] = make_float2(-xx.x, -xx.y);
        ((float2*)(out + 3 * (size_t)NSZ))[gdx] = a;
        ((float2*)(out + 4 * (size_t)NSZ))[gdx] = th;
    }
}

// ---- fallback (tiny ws): round-1 atomic path ----
__global__ __launch_bounds__(256)
void edge_kernel(const float* __restrict__ state, const int* __restrict__ row,
                 const int* __restrict__ col, const float* __restrict__ w,
                 float* __restrict__ agg) {
    int idx = blockIdx.x * blockDim.x + threadIdx.x;
    if (idx >= N_EDGES * 4) return;
    int e = idx >> 2, qq = idx & 3;
    int r = row[e], c = col[e];
    float we = w[e];
    const float4 xr = ((const float4*)state)[r * 4 + qq];
    const float4 xcv = ((const float4*)state)[c * 4 + qq];
    float* dst = agg + c * DIM + qq * 4;
    atomicAdd(dst + 0, sinf(xr.x - xcv.x) * we);
    atomicAdd(dst + 1, sinf(xr.y - xcv.y) * we);
    atomicAdd(dst + 2, sinf(xr.z - xcv.z) * we);
    atomicAdd(dst + 3, sinf(xr.w - xcv.w) * we);
}

__global__ __launch_bounds__(256)
void node_kernel(const float* __restrict__ state, const float* __restrict__ agg,
                 float* __restrict__ out) {
    int idx = blockIdx.x * blockDim.x + threadIdx.x;
    if (idx >= N_NODES * 4) return;
    float4 x = ((const float4*)state)[idx];
    float4 a = ((const float4*)agg)[idx];
    float4 tv = make_float4(tanhf(a.x), tanhf(a.y), tanhf(a.z), tanhf(a.w));
    ((float4*)(out + 0 * NSZ))[idx] = make_float4(tv.x - x.x, tv.y - x.y,
                                                  tv.z - x.z, tv.w - x.w);
    ((float4*)(out + 1 * NSZ))[idx] = x;
    ((float4*)(out + 2 * NSZ))[idx] = make_float4(-x.x, -x.y, -x.z, -x.w);
    ((float4*)(out + 4 * NSZ))[idx] = tv;
}

extern "C" void kernel_launch(void* const* d_in, const int* in_sizes, int n_in,
                              void* d_out, int out_size, void* d_ws, size_t ws_size,
                              hipStream_t stream) {
    const float* state = (const float*)d_in[0];
    const int*   row   = (const int*)d_in[1];
    const int*   col   = (const int*)d_in[2];
    const float* w     = (const float*)d_in[3];
    float* out = (float*)d_out;

    // ws layout: packed | hs | tableA | T   (every byte written before read;
    // no zero-init needed -> no memset)
    size_t packed_off = 0;
    size_t half_off   = packed_off + (size_t)N_EDGES * 8;          // 25.6MB
    size_t tblA_off   = half_off + (size_t)NSZ * 2;                // +3.2MB
    size_t tblT_off   = tblA_off + (size_t)NBUCK * NBLK * 2;       // +0.8MB
    size_t needed     = tblT_off + (size_t)NBUCK * NBLK * 2;       // +0.8MB

    if (ws_size >= needed) {
        unsigned long long* packed =
            (unsigned long long*)((char*)d_ws + packed_off);
        __half* hs = (__half*)((char*)d_ws + half_off);
        unsigned short* tableA = (unsigned short*)((char*)d_ws + tblA_off);
        unsigned short* T      = (unsigned short*)((char*)d_ws + tblT_off);

        to_half<<<(NSZ / 4 + 255) / 256, 256, 0, stream>>>(state, hs);
        local_sort<<<NBLK, 512, 0, stream>>>(row, col, w, packed, tableA);
        transpose_tbl<<<(NBUCK * NBLK + 255) / 256, 256, 0, stream>>>(tableA, T);
        seg_aggregate<<<NBUCK, 512, 0, stream>>>(
            state, (const __half2*)hs, packed, T, out);
    } else {
        float* agg = out + 3 * NSZ;
        (void)hipMemsetAsync(agg, 0, NSZ * sizeof(float), stream);
        edge_kernel<<<(N_EDGES * 4 + 255) / 256, 256, 0, stream>>>(
            state, row, col, w, agg);
        node_kernel<<<(N_NODES * 4 + 255) / 256, 256, 0, stream>>>(
            state, agg, out);
    }
}

// Round 10
// 217.327 us; speedup vs baseline: 1.2179x; 1.2179x over previous
//
#include <hip/hip_runtime.h>
#include <hip/hip_fp16.h>
#include <math.h>

#define N_NODES 100000
#define N_EDGES 3200000
#define DIM 16
#define NSZ (N_NODES * DIM)

#define NPB 128         // nodes per bucket (bucket = col>>7, cl = col&127)
#define NBUCK 782       // ceil(100000/128)
#define NBLK 512        // partition blocks
#define EPB 6250        // edges per partition block: 512*6250 = 3.2M exactly
#define CAP 6144        // aggregate LDS edge capacity (mean 4096, tiled if over)

typedef float nvec4 __attribute__((ext_vector_type(4)));

// ---- 0) state f32 -> f16 (3.2MB: per-XCD-L2 resident; halves gather bytes) ----
__global__ __launch_bounds__(256)
void to_half(const float* __restrict__ state, __half* __restrict__ hs) {
    int i = blockIdx.x * 256 + threadIdx.x;
    if (i >= NSZ / 4) return;
    nvec4 v = __builtin_nontemporal_load(&((const nvec4*)state)[i]);
    union { __half2 h[2]; float2 f; } u;
    u.h[0] = __floats2half2_rn(v.x, v.y);
    u.h[1] = __floats2half2_rn(v.z, v.w);
    ((float2*)hs)[i] = u.f;
}

// ---- 1) per-block bucket histogram -> count table tbl[bucket][blk] ----
__global__ __launch_bounds__(512)
void hist_table(const int* __restrict__ col, unsigned* __restrict__ tbl) {
    __shared__ int hcnt[NBUCK];
    int t = threadIdx.x, blk = blockIdx.x;
    int e0 = blk * EPB;
    for (int j = t; j < NBUCK; j += 512) hcnt[j] = 0;
    __syncthreads();
    for (int i = t; i < EPB; i += 512)
        atomicAdd(&hcnt[col[e0 + i] >> 7], 1);
    __syncthreads();
    for (int j = t; j < NBUCK; j += 512)
        tbl[(size_t)j * NBLK + blk] = (unsigned)hcnt[j];  // L2 merges 4B stores
}

// ---- 2a) per-bucket totals (one block per bucket, coalesced reduce) ----
__global__ __launch_bounds__(256)
void col_reduce(const unsigned* __restrict__ tbl, int* __restrict__ totals) {
    __shared__ int s[256];
    int b = blockIdx.x, t = threadIdx.x;
    int v = (int)tbl[(size_t)b * NBLK + t] + (int)tbl[(size_t)b * NBLK + 256 + t];
    s[t] = v;
    __syncthreads();
    for (int d = 128; d > 0; d >>= 1) {
        if (t < d) s[t] += s[t + d];
        __syncthreads();
    }
    if (t == 0) totals[b] = s[0];
}

// ---- 2b) exclusive scan of 782 totals -> off[783] (single block) ----
__global__ __launch_bounds__(1024)
void scan_off(const int* __restrict__ totals, int* __restrict__ off) {
    __shared__ int s[1024];
    int t = threadIdx.x;
    int v = (t < NBUCK) ? totals[t] : 0;
    s[t] = v;
    __syncthreads();
    for (int d = 1; d < 1024; d <<= 1) {
        int u = (t >= d) ? s[t - d] : 0;
        __syncthreads();
        s[t] += u;
        __syncthreads();
    }
    if (t < NBUCK) off[t + 1] = s[t];
    if (t == 0) off[0] = 0;
}

// ---- 2c) convert tbl[b][*] counts -> global write bases, in place ----
__global__ __launch_bounds__(512)
void base_scan(unsigned* __restrict__ tbl, const int* __restrict__ off) {
    __shared__ int s[512];
    int b = blockIdx.x, t = threadIdx.x;
    int v = (int)tbl[(size_t)b * NBLK + t];
    s[t] = v;
    __syncthreads();
    for (int d = 1; d < 512; d <<= 1) {
        int u = (t >= d) ? s[t - d] : 0;
        __syncthreads();
        s[t] += u;
        __syncthreads();
    }
    tbl[(size_t)b * NBLK + t] = (unsigned)(off[b] + s[t] - v);   // exclusive
}

// ---- 3) sort_write: LDS counting sort by bucket, write to PRECOMPUTED
//         global bases -> bucket-major sorted packed[]. Zero global atomics. ----
__global__ __launch_bounds__(512)
void sort_write(const int* __restrict__ row, const int* __restrict__ col,
                const float* __restrict__ w, const unsigned* __restrict__ tbl,
                unsigned long long* __restrict__ packed) {
    __shared__ unsigned long long sbuf[EPB];   // 50,000 B
    __shared__ int sc[1024];                   // scan scratch -> lstart
    __shared__ int hcnt[NBUCK];
    __shared__ int gbase[NBUCK];
    int t = threadIdx.x, blk = blockIdx.x;
    int e0 = blk * EPB;

    for (int j = t; j < NBUCK; j += 512) hcnt[j] = 0;
    __syncthreads();
    for (int i = t; i < EPB; i += 512)         // p1: histogram
        atomicAdd(&hcnt[col[e0 + i] >> 7], 1);
    for (int j = t; j < NBUCK; j += 512)       // fetch this block's bases
        gbase[j] = (int)tbl[(size_t)j * NBLK + blk];
    __syncthreads();
    sc[t]       = (t < NBUCK)       ? hcnt[t]       : 0;   // p2: scan 1024
    sc[t + 512] = (t + 512 < NBUCK) ? hcnt[t + 512] : 0;
    __syncthreads();
    for (int d = 1; d < 1024; d <<= 1) {
        int u1 = (t >= d) ? sc[t - d] : 0;
        int u2 = sc[t + 512 - d];
        __syncthreads();
        sc[t] += u1;
        sc[t + 512] += u2;
        __syncthreads();
    }
    for (int j = t; j < NBUCK; j += 512) {     // inclusive -> exclusive lstart
        sc[j] -= hcnt[j];
        hcnt[j] = 0;                           // reuse as intra-block cursor
    }
    __syncthreads();
    for (int i = t; i < EPB; i += 512) {       // p3: LDS scatter (sorted)
        int e = e0 + i;
        int c = col[e];
        int b = c >> 7;
        int pos = sc[b] + atomicAdd(&hcnt[b], 1);
        unsigned hi = ((unsigned)row[e] << 7) | (unsigned)(c & 127);
        sbuf[pos] = ((unsigned long long)hi << 32) | __float_as_uint(w[e]);
    }
    __syncthreads();
    // p4: linear sweep -> dense runs at deterministic global positions
    for (int i = t; i < EPB; i += 512) {
        int lo = 0, hi = NBUCK - 1;
        while (lo < hi) {                      // largest b with lstart[b] <= i
            int mid = (lo + hi + 1) >> 1;
            if (sc[mid] <= i) lo = mid; else hi = mid - 1;
        }
        __builtin_nontemporal_store(sbuf[i], &packed[gbase[lo] + (i - sc[lo])]);
    }
}

// ---- 4) per-bucket: coalesced read, in-LDS cl-sort, owner-computes regs ----
__global__ __launch_bounds__(512)
void bucket_sort_aggregate(const float* __restrict__ state,
                           const __half2* __restrict__ hs2,
                           const int* __restrict__ off,
                           const unsigned long long* __restrict__ packed,
                           float* __restrict__ out) {
    __shared__ unsigned long long sbuf[CAP];       // 48KB cl-sorted edges
    __shared__ int s_cnt[NPB], s_start[NPB], s_cur[NPB];
    int b = blockIdx.x, t = threadIdx.x;
    int g = t >> 3, q = t & 7;                     // 64 groups x 8 lanes
    int beg = off[b], end = off[b + 1];

    float2 acc[2] = {make_float2(0.f, 0.f), make_float2(0.f, 0.f)};
    float2 x2[2];
    int nn[2]; bool valid[2];
    #pragma unroll
    for (int r = 0; r < 2; ++r) {
        int n = b * NPB + r * 64 + g;
        valid[r] = (n < N_NODES);
        nn[r] = n;
        x2[r] = valid[r] ? ((const float2*)state)[n * 8 + q]
                         : make_float2(0.f, 0.f);
    }

    for (int tbeg = beg; tbeg < end; tbeg += CAP) {
        int tend = tbeg + CAP; if (tend > end) tend = end;
        if (t < NPB) s_cnt[t] = 0;
        __syncthreads();
        for (int e = tbeg + t; e < tend; e += 512) {   // coalesced
            unsigned hi = (unsigned)(packed[e] >> 32);
            atomicAdd(&s_cnt[hi & 127u], 1);
        }
        __syncthreads();
        if (t < NPB) s_start[t] = s_cnt[t];
        __syncthreads();
        for (int d = 1; d < NPB; d <<= 1) {
            int u = 0;
            if (t < NPB && t >= d) u = s_start[t - d];
            __syncthreads();
            if (t < NPB) s_start[t] += u;
            __syncthreads();
        }
        if (t < NPB) {
            int ex = s_start[t] - s_cnt[t];
            s_start[t] = ex;
            s_cur[t] = ex;
        }
        __syncthreads();
        for (int e = tbeg + t; e < tend; e += 512) {   // coalesced, L2-hot
            unsigned long long p = packed[e];
            int cl = (int)((p >> 32) & 127u);
            int pos = atomicAdd(&s_cur[cl], 1);
            sbuf[pos] = p;
        }
        __syncthreads();
        #pragma unroll
        for (int r = 0; r < 2; ++r) {
            int j = r * 64 + g;
            int es = s_start[j], ee = s_cur[j];
            float2 a = acc[r], xx = x2[r];
            for (int e = es; e < ee; ++e) {
                unsigned long long p = sbuf[e];        // 8-lane broadcast
                float we = __uint_as_float((unsigned)p);
                int rn = (int)(p >> 39);
                float2 f = __half22float2(hs2[rn * 8 + q]);   // 32B/group
                a.x += __sinf(f.x - xx.x) * we;
                a.y += __sinf(f.y - xx.y) * we;
            }
            acc[r] = a;
        }
        __syncthreads();
    }

    #pragma unroll
    for (int r = 0; r < 2; ++r) {
        if (!valid[r]) continue;
        float2 a = acc[r], xx = x2[r];
        float2 th = make_float2(tanhf(a.x), tanhf(a.y));
        int gdx = nn[r] * 8 + q;
        ((float2*)(out + 0 * (size_t)NSZ))[gdx] = make_float2(th.x - xx.x, th.y - xx.y);
        ((float2*)(out + 1 * (size_t)NSZ))[gdx] = xx;
        ((float2*)(out + 2 * (size_t)NSZ))[gdx] = make_float2(-xx.x, -xx.y);
        ((float2*)(out + 3 * (size_t)NSZ))[gdx] = a;
        ((float2*)(out + 4 * (size_t)NSZ))[gdx] = th;
    }
}

// ---- fallback (tiny ws): round-1 atomic path ----
__global__ __launch_bounds__(256)
void edge_kernel(const float* __restrict__ state, const int* __restrict__ row,
                 const int* __restrict__ col, const float* __restrict__ w,
                 float* __restrict__ agg) {
    int idx = blockIdx.x * blockDim.x + threadIdx.x;
    if (idx >= N_EDGES * 4) return;
    int e = idx >> 2, qq = idx & 3;
    int r = row[e], c = col[e];
    float we = w[e];
    const float4 xr = ((const float4*)state)[r * 4 + qq];
    const float4 xcv = ((const float4*)state)[c * 4 + qq];
    float* dst = agg + c * DIM + qq * 4;
    atomicAdd(dst + 0, sinf(xr.x - xcv.x) * we);
    atomicAdd(dst + 1, sinf(xr.y - xcv.y) * we);
    atomicAdd(dst + 2, sinf(xr.z - xcv.z) * we);
    atomicAdd(dst + 3, sinf(xr.w - xcv.w) * we);
}

__global__ __launch_bounds__(256)
void node_kernel(const float* __restrict__ state, const float* __restrict__ agg,
                 float* __restrict__ out) {
    int idx = blockIdx.x * blockDim.x + threadIdx.x;
    if (idx >= N_NODES * 4) return;
    float4 x = ((const float4*)state)[idx];
    float4 a = ((const float4*)agg)[idx];
    float4 tv = make_float4(tanhf(a.x), tanhf(a.y), tanhf(a.z), tanhf(a.w));
    ((float4*)(out + 0 * NSZ))[idx] = make_float4(tv.x - x.x, tv.y - x.y,
                                                  tv.z - x.z, tv.w - x.w);
    ((float4*)(out + 1 * NSZ))[idx] = x;
    ((float4*)(out + 2 * NSZ))[idx] = make_float4(-x.x, -x.y, -x.z, -x.w);
    ((float4*)(out + 4 * NSZ))[idx] = tv;
}

extern "C" void kernel_launch(void* const* d_in, const int* in_sizes, int n_in,
                              void* d_out, int out_size, void* d_ws, size_t ws_size,
                              hipStream_t stream) {
    const float* state = (const float*)d_in[0];
    const int*   row   = (const int*)d_in[1];
    const int*   col   = (const int*)d_in[2];
    const float* w     = (const float*)d_in[3];
    float* out = (float*)d_out;

    // ws: packed | hs | tbl | totals | off  (every byte written before read)
    size_t packed_off = 0;
    size_t half_off   = packed_off + (size_t)N_EDGES * 8;          // 25.6MB
    size_t tbl_off    = half_off + (size_t)NSZ * 2;                // +3.2MB
    size_t tot_off    = tbl_off + (size_t)NBUCK * NBLK * 4;        // +1.6MB
    size_t off_off    = tot_off + (size_t)NBUCK * 4;
    size_t needed     = off_off + (size_t)(NBUCK + 1) * 4;

    if (ws_size >= needed) {
        unsigned long long* packed =
            (unsigned long long*)((char*)d_ws + packed_off);
        __half* hs   = (__half*)((char*)d_ws + half_off);
        unsigned* tbl = (unsigned*)((char*)d_ws + tbl_off);
        int* totals  = (int*)((char*)d_ws + tot_off);
        int* off     = (int*)((char*)d_ws + off_off);

        to_half<<<(NSZ / 4 + 255) / 256, 256, 0, stream>>>(state, hs);
        hist_table<<<NBLK, 512, 0, stream>>>(col, tbl);
        col_reduce<<<NBUCK, 256, 0, stream>>>(tbl, totals);
        scan_off<<<1, 1024, 0, stream>>>(totals, off);
        base_scan<<<NBUCK, 512, 0, stream>>>(tbl, off);
        sort_write<<<NBLK, 512, 0, stream>>>(row, col, w, tbl, packed);
        bucket_sort_aggregate<<<NBUCK, 512, 0, stream>>>(
            state, (const __half2*)hs, off, packed, out);
    } else {
        float* agg = out + 3 * NSZ;
        (void)hipMemsetAsync(agg, 0, NSZ * sizeof(float), stream);
        edge_kernel<<<(N_EDGES * 4 + 255) / 256, 256, 0, stream>>>(
            state, row, col, w, agg);
        node_kernel<<<(N_NODES * 4 + 255) / 256, 256, 0, stream>>>(
            state, agg, out);
    }
}

// Round 11
// 210.557 us; speedup vs baseline: 1.2571x; 1.0322x over previous
//
#include <hip/hip_runtime.h>
#include <hip/hip_fp16.h>
#include <math.h>

#define N_NODES 100000
#define N_EDGES 3200000
#define DIM 16
#define NSZ (N_NODES * DIM)

#define NPB 128         // nodes per bucket (bucket = col>>7, cl = col&127)
#define NBUCK 782       // ceil(100000/128)
#define NBLK 512        // partition blocks
#define EPB 6250        // edges per partition block: 512*6250 = 3.2M exactly
#define CAP 6144        // aggregate LDS edge capacity (mean 4096, tiled if over)

// packed entry: [63:47]=col(17) [46:30]=row(17) [29:0]=w bits>>2
typedef float nvec4 __attribute__((ext_vector_type(4)));

// ---- 1) fused: f32->f16 convert + per-block bucket histogram -> tbl[bucket][blk]
__global__ __launch_bounds__(512)
void hist_table(const float* __restrict__ state, __half* __restrict__ hs,
                const int* __restrict__ col, unsigned* __restrict__ tbl) {
    __shared__ int hcnt[NBUCK];
    int t = threadIdx.x, blk = blockIdx.x;
    for (int j = t; j < NBUCK; j += 512) hcnt[j] = 0;
    for (int i = blk * 512 + t; i < NSZ / 4; i += NBLK * 512) {
        nvec4 v = __builtin_nontemporal_load(&((const nvec4*)state)[i]);
        union { __half2 h[2]; float2 f; } u;
        u.h[0] = __floats2half2_rn(v.x, v.y);
        u.h[1] = __floats2half2_rn(v.z, v.w);
        ((float2*)hs)[i] = u.f;
    }
    __syncthreads();
    int e0 = blk * EPB;
    for (int i = t; i < EPB; i += 512)
        atomicAdd(&hcnt[col[e0 + i] >> 7], 1);
    __syncthreads();
    for (int j = t; j < NBUCK; j += 512)
        tbl[(size_t)j * NBLK + blk] = (unsigned)hcnt[j];
}

// ---- 2a) per-bucket totals ----
__global__ __launch_bounds__(256)
void col_reduce(const unsigned* __restrict__ tbl, int* __restrict__ totals) {
    __shared__ int s[256];
    int b = blockIdx.x, t = threadIdx.x;
    int v = (int)tbl[(size_t)b * NBLK + t] + (int)tbl[(size_t)b * NBLK + 256 + t];
    s[t] = v;
    __syncthreads();
    for (int d = 128; d > 0; d >>= 1) {
        if (t < d) s[t] += s[t + d];
        __syncthreads();
    }
    if (t == 0) totals[b] = s[0];
}

// ---- 2b) exclusive scan of 782 totals -> off[783] ----
__global__ __launch_bounds__(1024)
void scan_off(const int* __restrict__ totals, int* __restrict__ off) {
    __shared__ int s[1024];
    int t = threadIdx.x;
    int v = (t < NBUCK) ? totals[t] : 0;
    s[t] = v;
    __syncthreads();
    for (int d = 1; d < 1024; d <<= 1) {
        int u = (t >= d) ? s[t - d] : 0;
        __syncthreads();
        s[t] += u;
        __syncthreads();
    }
    if (t < NBUCK) off[t + 1] = s[t];
    if (t == 0) off[0] = 0;
}

// ---- 2c) tbl counts -> global write bases, in place ----
__global__ __launch_bounds__(512)
void base_scan(unsigned* __restrict__ tbl, const int* __restrict__ off) {
    __shared__ int s[512];
    int b = blockIdx.x, t = threadIdx.x;
    int v = (int)tbl[(size_t)b * NBLK + t];
    s[t] = v;
    __syncthreads();
    for (int d = 1; d < 512; d <<= 1) {
        int u = (t >= d) ? s[t - d] : 0;
        __syncthreads();
        s[t] += u;
        __syncthreads();
    }
    tbl[(size_t)b * NBLK + t] = (unsigned)(off[b] + s[t] - v);   // exclusive
}

// ---- 3) sort_write: counts DERIVED from tbl (no re-histogram), LDS scatter,
//         dense sweep with bucket decoded from the entry (no binary search) ----
__global__ __launch_bounds__(512)
void sort_write(const int* __restrict__ row, const int* __restrict__ col,
                const float* __restrict__ w, const unsigned* __restrict__ tbl,
                const int* __restrict__ off,
                unsigned long long* __restrict__ packed) {
    __shared__ unsigned long long sbuf[EPB];   // 50,000 B
    __shared__ int sc[1024];                   // scan scratch -> lstart
    __shared__ int cur[NBUCK];                 // counts -> scatter cursor
    __shared__ int gbase[NBUCK];
    int t = threadIdx.x, blk = blockIdx.x;
    int e0 = blk * EPB;

    for (int j = t; j < NBUCK; j += 512) {     // bases + derived counts
        int b0 = (int)tbl[(size_t)j * NBLK + blk];
        int b1 = (blk == NBLK - 1) ? off[j + 1]
                                   : (int)tbl[(size_t)j * NBLK + blk + 1];
        gbase[j] = b0;
        cur[j] = b1 - b0;                      // count
    }
    __syncthreads();
    sc[t]       = (t < NBUCK)       ? cur[t]       : 0;
    sc[t + 512] = (t + 512 < NBUCK) ? cur[t + 512] : 0;
    __syncthreads();
    for (int d = 1; d < 1024; d <<= 1) {
        int u1 = (t >= d) ? sc[t - d] : 0;
        int u2 = sc[t + 512 - d];              // t+512 >= d always
        __syncthreads();
        sc[t] += u1;
        sc[t + 512] += u2;
        __syncthreads();
    }
    for (int j = t; j < NBUCK; j += 512) {     // inclusive -> exclusive
        int ex = sc[j] - cur[j];
        sc[j] = ex;                            // lstart (persist for sweep)
        cur[j] = ex;                           // scatter cursor
    }
    __syncthreads();
    for (int i = t; i < EPB; i += 512) {       // single edge pass: LDS scatter
        int e = e0 + i;
        int c = col[e];
        int pos = atomicAdd(&cur[c >> 7], 1);
        sbuf[pos] = ((unsigned long long)(unsigned)c << 47)
                  | ((unsigned long long)(unsigned)row[e] << 30)
                  | (unsigned long long)(__float_as_uint(w[e]) >> 2);
    }
    __syncthreads();
    for (int i = t; i < EPB; i += 512) {       // dense sweep; bucket from entry
        unsigned long long pv = sbuf[i];
        int b = (int)(pv >> 54);               // col>>7
        __builtin_nontemporal_store(pv, &packed[gbase[b] + (i - sc[b])]);
    }
}

// ---- 4) per-bucket: coalesced read, in-LDS cl-sort, owner-computes regs ----
__global__ __launch_bounds__(512)
void bucket_sort_aggregate(const float* __restrict__ state,
                           const __half2* __restrict__ hs2,
                           const int* __restrict__ off,
                           const unsigned long long* __restrict__ packed,
                           float* __restrict__ out) {
    __shared__ unsigned long long sbuf[CAP];       // 48KB cl-sorted edges
    __shared__ int s_cnt[NPB], s_start[NPB], s_cur[NPB];
    int b = blockIdx.x, t = threadIdx.x;
    int g = t >> 3, q = t & 7;                     // 64 groups x 8 lanes
    int beg = off[b], end = off[b + 1];

    float2 acc[2] = {make_float2(0.f, 0.f), make_float2(0.f, 0.f)};
    float2 x2[2];
    int nn[2]; bool valid[2];
    #pragma unroll
    for (int r = 0; r < 2; ++r) {
        int n = b * NPB + r * 64 + g;
        valid[r] = (n < N_NODES);
        nn[r] = n;
        x2[r] = valid[r] ? ((const float2*)state)[n * 8 + q]
                         : make_float2(0.f, 0.f);
    }

    for (int tbeg = beg; tbeg < end; tbeg += CAP) {
        int tend = tbeg + CAP; if (tend > end) tend = end;
        if (t < NPB) s_cnt[t] = 0;
        __syncthreads();
        for (int e = tbeg + t; e < tend; e += 512) {   // coalesced hi-word read
            unsigned hi = (unsigned)(packed[e] >> 32);
            atomicAdd(&s_cnt[(hi >> 15) & 127u], 1);   // cl = bits[21:15] of hi
        }
        __syncthreads();
        if (t < NPB) s_start[t] = s_cnt[t];
        __syncthreads();
        for (int d = 1; d < NPB; d <<= 1) {
            int u = 0;
            if (t < NPB && t >= d) u = s_start[t - d];
            __syncthreads();
            if (t < NPB) s_start[t] += u;
            __syncthreads();
        }
        if (t < NPB) {
            int ex = s_start[t] - s_cnt[t];
            s_start[t] = ex;
            s_cur[t] = ex;
        }
        __syncthreads();
        for (int e = tbeg + t; e < tend; e += 512) {   // coalesced, L2-hot
            unsigned long long p = packed[e];
            int cl = (int)((p >> 47) & 127u);
            int pos = atomicAdd(&s_cur[cl], 1);
            sbuf[pos] = p;
        }
        __syncthreads();
        #pragma unroll
        for (int r = 0; r < 2; ++r) {
            int j = r * 64 + g;
            int es = s_start[j], ee = s_cur[j];
            float2 a = acc[r], xx = x2[r];
            for (int e = es; e < ee; ++e) {
                unsigned long long p = sbuf[e];        // 8-lane broadcast
                float we = __uint_as_float(((unsigned)p & 0x3FFFFFFFu) << 2);
                int rn = (int)((p >> 30) & 0x1FFFFu);
                float2 f = __half22float2(hs2[rn * 8 + q]);   // 32B/group
                a.x += __sinf(f.x - xx.x) * we;
                a.y += __sinf(f.y - xx.y) * we;
            }
            acc[r] = a;
        }
        __syncthreads();
    }

    #pragma unroll
    for (int r = 0; r < 2; ++r) {
        if (!valid[r]) continue;
        float2 a = acc[r], xx = x2[r];
        float2 th = make_float2(tanhf(a.x), tanhf(a.y));
        int gdx = nn[r] * 8 + q;
        ((float2*)(out + 0 * (size_t)NSZ))[gdx] = make_float2(th.x - xx.x, th.y - xx.y);
        ((float2*)(out + 1 * (size_t)NSZ))[gdx] = xx;
        ((float2*)(out + 2 * (size_t)NSZ))[gdx] = make_float2(-xx.x, -xx.y);
        ((float2*)(out + 3 * (size_t)NSZ))[gdx] = a;
        ((float2*)(out + 4 * (size_t)NSZ))[gdx] = th;
    }
}

// ---- fallback (tiny ws): round-1 atomic path ----
__global__ __launch_bounds__(256)
void edge_kernel(const float* __restrict__ state, const int* __restrict__ row,
                 const int* __restrict__ col, const float* __restrict__ w,
                 float* __restrict__ agg) {
    int idx = blockIdx.x * blockDim.x + threadIdx.x;
    if (idx >= N_EDGES * 4) return;
    int e = idx >> 2, qq = idx & 3;
    int r = row[e], c = col[e];
    float we = w[e];
    const float4 xr = ((const float4*)state)[r * 4 + qq];
    const float4 xcv = ((const float4*)state)[c * 4 + qq];
    float* dst = agg + c * DIM + qq * 4;
    atomicAdd(dst + 0, sinf(xr.x - xcv.x) * we);
    atomicAdd(dst + 1, sinf(xr.y - xcv.y) * we);
    atomicAdd(dst + 2, sinf(xr.z - xcv.z) * we);
    atomicAdd(dst + 3, sinf(xr.w - xcv.w) * we);
}

__global__ __launch_bounds__(256)
void node_kernel(const float* __restrict__ state, const float* __restrict__ agg,
                 float* __restrict__ out) {
    int idx = blockIdx.x * blockDim.x + threadIdx.x;
    if (idx >= N_NODES * 4) return;
    float4 x = ((const float4*)state)[idx];
    float4 a = ((const float4*)agg)[idx];
    float4 tv = make_float4(tanhf(a.x), tanhf(a.y), tanhf(a.z), tanhf(a.w));
    ((float4*)(out + 0 * NSZ))[idx] = make_float4(tv.x - x.x, tv.y - x.y,
                                                  tv.z - x.z, tv.w - x.w);
    ((float4*)(out + 1 * NSZ))[idx] = x;
    ((float4*)(out + 2 * NSZ))[idx] = make_float4(-x.x, -x.y, -x.z, -x.w);
    ((float4*)(out + 4 * NSZ))[idx] = tv;
}

extern "C" void kernel_launch(void* const* d_in, const int* in_sizes, int n_in,
                              void* d_out, int out_size, void* d_ws, size_t ws_size,
                              hipStream_t stream) {
    const float* state = (const float*)d_in[0];
    const int*   row   = (const int*)d_in[1];
    const int*   col   = (const int*)d_in[2];
    const float* w     = (const float*)d_in[3];
    float* out = (float*)d_out;

    // ws: packed | hs | tbl | totals | off  (every byte written before read)
    size_t packed_off = 0;
    size_t half_off   = packed_off + (size_t)N_EDGES * 8;          // 25.6MB
    size_t tbl_off    = half_off + (size_t)NSZ * 2;                // +3.2MB
    size_t tot_off    = tbl_off + (size_t)NBUCK * NBLK * 4;        // +1.6MB
    size_t off_off    = tot_off + (size_t)NBUCK * 4;
    size_t needed     = off_off + (size_t)(NBUCK + 1) * 4;

    if (ws_size >= needed) {
        unsigned long long* packed =
            (unsigned long long*)((char*)d_ws + packed_off);
        __half* hs    = (__half*)((char*)d_ws + half_off);
        unsigned* tbl = (unsigned*)((char*)d_ws + tbl_off);
        int* totals   = (int*)((char*)d_ws + tot_off);
        int* off      = (int*)((char*)d_ws + off_off);

        hist_table<<<NBLK, 512, 0, stream>>>(state, hs, col, tbl);
        col_reduce<<<NBUCK, 256, 0, stream>>>(tbl, totals);
        scan_off<<<1, 1024, 0, stream>>>(totals, off);
        base_scan<<<NBUCK, 512, 0, stream>>>(tbl, off);
        sort_write<<<NBLK, 512, 0, stream>>>(row, col, w, tbl, off, packed);
        bucket_sort_aggregate<<<NBUCK, 512, 0, stream>>>(
            state, (const __half2*)hs, off, packed, out);
    } else {
        float* agg = out + 3 * NSZ;
        (void)hipMemsetAsync(agg, 0, NSZ * sizeof(float), stream);
        edge_kernel<<<(N_EDGES * 4 + 255) / 256, 256, 0, stream>>>(
            state, row, col, w, agg);
        node_kernel<<<(N_NODES * 4 + 255) / 256, 256, 0, stream>>>(
            state, agg, out);
    }
}